// Round 5
// baseline (1222.881 us; speedup 1.0000x reference)
//
#include <hip/hip_runtime.h>
#include <math.h>

constexpr int N_NODES = 40000;
constexpr int N_EDGES = 500000;
constexpr int ETOT    = N_EDGES + N_NODES;
constexpr int IN_DIM  = 128;
constexpr int ED_DIM  = 16;
constexpr int FEAT    = 256;   // H*C for every layer
constexpr int BATCH   = 128;
constexpr float NEG   = 0.2f;
constexpr int NCHUNK  = (N_NODES + 255) / 256;  // 157

typedef float vfloat16 __attribute__((ext_vector_type(16)));

// ---------------- CSR build (by dst, incl. self loops) ----------------
__global__ __launch_bounds__(256) void k_deg(const int* __restrict__ dst, int* __restrict__ deg)
{
    int e = blockIdx.x * 256 + threadIdx.x;
    if (e >= ETOT) return;
    int v = e < N_EDGES ? dst[e] : e - N_EDGES;
    atomicAdd(&deg[v], 1);
}

__global__ __launch_bounds__(256) void k_scan1(const int* __restrict__ deg, int* __restrict__ bsum)
{
    __shared__ int s[256];
    int t = threadIdx.x;
    int idx = blockIdx.x * 256 + t;
    s[t] = idx < N_NODES ? deg[idx] : 0;
    __syncthreads();
    for (int st = 128; st; st >>= 1) { if (t < st) s[t] += s[t + st]; __syncthreads(); }
    if (t == 0) bsum[blockIdx.x] = s[0];
}

__global__ __launch_bounds__(256) void k_scan2(const int* __restrict__ bsum,
    int* __restrict__ boff, int* __restrict__ rowptr)
{
    __shared__ int s[256];
    int t = threadIdx.x;
    int v = t < NCHUNK ? bsum[t] : 0;
    s[t] = v;
    __syncthreads();
    for (int off = 1; off < 256; off <<= 1) {
        int x = (t >= off) ? s[t - off] : 0;
        __syncthreads();
        s[t] += x;
        __syncthreads();
    }
    if (t < NCHUNK) boff[t] = s[t] - v;
    if (t == 0) rowptr[N_NODES] = ETOT;
}

__global__ __launch_bounds__(256) void k_scan3(const int* __restrict__ deg,
    const int* __restrict__ boff, int* __restrict__ rowptr)
{
    __shared__ int s[256];
    int t = threadIdx.x;
    int idx = blockIdx.x * 256 + t;
    int v = idx < N_NODES ? deg[idx] : 0;
    s[t] = v;
    __syncthreads();
    for (int off = 1; off < 256; off <<= 1) {
        int x = (t >= off) ? s[t - off] : 0;
        __syncthreads();
        s[t] += x;
        __syncthreads();
    }
    if (idx < N_NODES) rowptr[idx] = boff[blockIdx.x] + s[t] - v;
}

// elist2[pos] = (src, eid): kills the dependent srcArr gather in k_gat
__global__ __launch_bounds__(256) void k_fill(const int* __restrict__ srcA, const int* __restrict__ dst,
    const int* __restrict__ rowptr, int* __restrict__ fill, int2* __restrict__ elist2)
{
    int e = blockIdx.x * 256 + threadIdx.x;
    if (e >= ETOT) return;
    int v = e < N_EDGES ? dst[e]  : e - N_EDGES;
    int s = e < N_EDGES ? srcA[e] : e - N_EDGES;
    int pos = rowptr[v] + atomicAdd(&fill[v], 1);
    elist2[pos] = make_int2(s, e);
}

// ---------------- self-loop mean edge attr via CSR (no atomics) ----------------
__global__ __launch_bounds__(256) void k_loop_csr(const int2* __restrict__ elist2,
    const int* __restrict__ rowptr, const float* __restrict__ ea, float* __restrict__ loop_attr)
{
    int t = blockIdx.x * 256 + threadIdx.x;
    if (t >= N_NODES * ED_DIM) return;
    int n = t >> 4, d = t & 15;
    int p0 = rowptr[n], p1 = rowptr[n + 1];
    float s = 0.f; int c = 0;
    for (int p = p0; p < p1; ++p) {
        int e = elist2[p].y;
        if (e < N_EDGES) { s += ea[(size_t)e * ED_DIM + d]; ++c; }
    }
    loop_attr[t] = s / (float)(c > 0 ? c : 1);
}

// ---------------- fp32 GEMM: C[M,N] = A[M,K] @ W[K,N] + bias (+relu) ----------------
// 128x128 tile, 256 threads, 8x8 acc/thread, global->reg prefetch of next K-tile.
__global__ __launch_bounds__(256) void k_gemm(const float* __restrict__ A, const float* __restrict__ W,
    const float* __restrict__ bias, float* __restrict__ C, int M, int N, int K, int act)
{
    __shared__ float As[16][136];   // [k][m]
    __shared__ float Bs[16][136];   // [k][n]
    int t = threadIdx.x;
    int bm = blockIdx.x * 128, bn = blockIdx.y * 128;
    int tr = t >> 4, tc = t & 15;
    int mr0 = tr * 8, nc0 = tc * 4;

    // staging coords
    int ar0 = t >> 1,        ak0 = (t & 1) << 3;   // 128 rows x 2 threads x 8 floats
    int bk0 = t >> 5,        bn0 = (t & 31) << 2;  // 16 k x 32 threads x 4 floats

    float acc[8][8] = {};

    // prefetch tile 0
    int r0 = bm + ar0; r0 = r0 < M ? r0 : M - 1;
    float4 avA = *(const float4*)(A + (size_t)r0 * K + ak0);
    float4 avB = *(const float4*)(A + (size_t)r0 * K + ak0 + 4);
    float4 bvA = *(const float4*)(W + (size_t)bk0 * N + bn + bn0);
    float4 bvB = *(const float4*)(W + (size_t)(bk0 + 8) * N + bn + bn0);

    for (int k0 = 0; k0 < K; k0 += 16) {
        __syncthreads();
        As[ak0 + 0][ar0] = avA.x; As[ak0 + 1][ar0] = avA.y;
        As[ak0 + 2][ar0] = avA.z; As[ak0 + 3][ar0] = avA.w;
        As[ak0 + 4][ar0] = avB.x; As[ak0 + 5][ar0] = avB.y;
        As[ak0 + 6][ar0] = avB.z; As[ak0 + 7][ar0] = avB.w;
        *(float4*)&Bs[bk0][bn0]     = bvA;
        *(float4*)&Bs[bk0 + 8][bn0] = bvB;
        __syncthreads();
        // prefetch next tile while computing this one
        if (k0 + 16 < K) {
            avA = *(const float4*)(A + (size_t)r0 * K + k0 + 16 + ak0);
            avB = *(const float4*)(A + (size_t)r0 * K + k0 + 16 + ak0 + 4);
            bvA = *(const float4*)(W + (size_t)(k0 + 16 + bk0) * N + bn + bn0);
            bvB = *(const float4*)(W + (size_t)(k0 + 24 + bk0) * N + bn + bn0);
        }
        #pragma unroll
        for (int k = 0; k < 16; ++k) {
            float4 a0 = *(const float4*)&As[k][mr0];
            float4 a1 = *(const float4*)&As[k][mr0 + 4];
            float4 b0 = *(const float4*)&Bs[k][nc0];
            float4 b1 = *(const float4*)&Bs[k][64 + nc0];
            float am[8] = {a0.x, a0.y, a0.z, a0.w, a1.x, a1.y, a1.z, a1.w};
            float bv[8] = {b0.x, b0.y, b0.z, b0.w, b1.x, b1.y, b1.z, b1.w};
            #pragma unroll
            for (int i = 0; i < 8; ++i)
                #pragma unroll
                for (int j = 0; j < 8; ++j)
                    acc[i][j] = fmaf(am[i], bv[j], acc[i][j]);
        }
    }

    float bb[8];
    #pragma unroll
    for (int j = 0; j < 4; ++j) { bb[j] = bias[bn + nc0 + j]; bb[j + 4] = bias[bn + 64 + nc0 + j]; }
    #pragma unroll
    for (int i = 0; i < 8; ++i) {
        int row = bm + mr0 + i;
        if (row >= M) break;
        float4 o0, o1;
        o0.x = acc[i][0] + bb[0]; o0.y = acc[i][1] + bb[1];
        o0.z = acc[i][2] + bb[2]; o0.w = acc[i][3] + bb[3];
        o1.x = acc[i][4] + bb[4]; o1.y = acc[i][5] + bb[5];
        o1.z = acc[i][6] + bb[6]; o1.w = acc[i][7] + bb[7];
        if (act) {
            o0.x = fmaxf(o0.x, 0.f); o0.y = fmaxf(o0.y, 0.f); o0.z = fmaxf(o0.z, 0.f); o0.w = fmaxf(o0.w, 0.f);
            o1.x = fmaxf(o1.x, 0.f); o1.y = fmaxf(o1.y, 0.f); o1.z = fmaxf(o1.z, 0.f); o1.w = fmaxf(o1.w, 0.f);
        }
        *(float4*)(C + (size_t)row * N + bn + nc0)      = o0;
        *(float4*)(C + (size_t)row * N + bn + 64 + nc0) = o1;
    }
}

static void launch_gemm(const float* A, const float* W, const float* bias, float* C,
                        int M, int N, int K, int act, hipStream_t stream)
{
    dim3 grid((M + 127) / 128, N / 128);
    k_gemm<<<grid, 256, 0, stream>>>(A, W, bias, C, M, N, K, act);
}

// ---------------- fused GATv2: one wave per dst node, quarter-wave head layout ----------------
// channel idx(j) = q*64 + u + 16*j, q = lane>>4 (== head for H=4), u = lane&15.
// We held as 4x float16 vectors, pinned in arch VGPRs every loop iteration via asm.

#define XELOAD(s) do {                                                                \
    int src_ = eS[s].x, e_ = eS[s].y;                                                 \
    const float4* eb4_ = reinterpret_cast<const float4*>(                             \
        (e_ < N_EDGES) ? ea + (size_t)e_ * ED_DIM                                     \
                       : loop_attr + (size_t)src_ * ED_DIM);                          \
    evS[s][0] = eb4_[0]; evS[s][1] = eb4_[1];                                         \
    evS[s][2] = eb4_[2]; evS[s][3] = eb4_[3];                                         \
    const float* xp_ = xl + (size_t)src_ * FEAT + base;                               \
    xlvS[s][0] = xp_[0];  xlvS[s][1] = xp_[16];                                       \
    xlvS[s][2] = xp_[32]; xlvS[s][3] = xp_[48];                                       \
} while (0)

#define COMPUTE(s) do {                                                               \
    float ef0_ = 0.f, ef1_ = 0.f, ef2_ = 0.f, ef3_ = 0.f;                             \
    const float* ed_ = (const float*)evS[s];                                          \
    _Pragma("unroll")                                                                 \
    for (int d_ = 0; d_ < ED_DIM; ++d_) {                                             \
        float a_ = ed_[d_];                                                           \
        ef0_ = fmaf(a_, weV0[d_], ef0_); ef1_ = fmaf(a_, weV1[d_], ef1_);             \
        ef2_ = fmaf(a_, weV2[d_], ef2_); ef3_ = fmaf(a_, weV3[d_], ef3_);             \
    }                                                                                 \
    float s0_ = xlvS[s][0] + xrv[0] + ef0_;                                           \
    float s1_ = xlvS[s][1] + xrv[1] + ef1_;                                           \
    float s2_ = xlvS[s][2] + xrv[2] + ef2_;                                           \
    float s3_ = xlvS[s][3] + xrv[3] + ef3_;                                           \
    s0_ = fmaxf(s0_, 0.f) + NEG * fminf(s0_, 0.f);                                    \
    s1_ = fmaxf(s1_, 0.f) + NEG * fminf(s1_, 0.f);                                    \
    s2_ = fmaxf(s2_, 0.f) + NEG * fminf(s2_, 0.f);                                    \
    s3_ = fmaxf(s3_, 0.f) + NEG * fminf(s3_, 0.f);                                    \
    float l_ = fmaf(s0_, attR[0], fmaf(s1_, attR[1], fmaf(s2_, attR[2], s3_ * attR[3])));\
    l_ += __shfl_xor(l_, 1, 64);                                                      \
    l_ += __shfl_xor(l_, 2, 64);                                                      \
    l_ += __shfl_xor(l_, 4, 64);                                                      \
    l_ += __shfl_xor(l_, 8, 64);                                                      \
    if (H == 1) { l_ += __shfl_xor(l_, 16, 64); l_ += __shfl_xor(l_, 32, 64); }       \
    float nm_ = fmaxf(m, l_);                                                         \
    float sc_ = __expf(m - nm_);                                                      \
    float w_  = __expf(l_ - nm_);                                                     \
    z = fmaf(z, sc_, w_);                                                             \
    m = nm_;                                                                          \
    acc[0] = fmaf(acc[0], sc_, w_ * xlvS[s][0]);                                      \
    acc[1] = fmaf(acc[1], sc_, w_ * xlvS[s][1]);                                      \
    acc[2] = fmaf(acc[2], sc_, w_ * xlvS[s][2]);                                      \
    acc[3] = fmaf(acc[3], sc_, w_ * xlvS[s][3]);                                      \
} while (0)

#define PIN_WE() asm volatile("" : "+v"(weV0), "+v"(weV1), "+v"(weV2), "+v"(weV3))

template <int H, int RELU>
__global__ __launch_bounds__(256, 3) void k_gat(
    const float* __restrict__ xl, const float* __restrict__ xr,
    const float* __restrict__ ea, const float* __restrict__ loop_attr,
    const int2* __restrict__ elist2, const int* __restrict__ rowptr,
    const float* __restrict__ We, const float* __restrict__ att,
    const float* __restrict__ bias, float* __restrict__ out)
{
    int t = threadIdx.x;
    int lane = t & 63;
    int n = __builtin_amdgcn_readfirstlane(blockIdx.x * 4 + (t >> 6));
    int q = lane >> 4;
    int u = lane & 15;
    int base = q * 64 + u;

    vfloat16 weV0, weV1, weV2, weV3;
    #pragma unroll
    for (int d = 0; d < ED_DIM; ++d) {
        weV0[d] = We[d * FEAT + base];
        weV1[d] = We[d * FEAT + base + 16];
        weV2[d] = We[d * FEAT + base + 32];
        weV3[d] = We[d * FEAT + base + 48];
    }
    PIN_WE();

    float attR[4], xrv[4];
    #pragma unroll
    for (int j = 0; j < 4; ++j) {
        attR[j] = att[base + 16 * j];
        xrv[j]  = xr[(size_t)n * FEAT + base + 16 * j];
    }

    float m = -INFINITY, z = 0.f;
    float acc[4] = {0.f, 0.f, 0.f, 0.f};

    int p0 = rowptr[n], p1 = rowptr[n + 1];   // p1 > p0 guaranteed (self-loop)
    int pe = p1 - 1;

    int2   eS[2];
    float4 evS[2][4];
    float  xlvS[2][4];

    eS[0] = elist2[p0];
    { int pc = p0 + 1 > pe ? pe : p0 + 1; eS[1] = elist2[pc]; }
    XELOAD(0);

    int p = p0;
    while (true) {
        PIN_WE();   // every iteration: keeping We in arch VGPRs must beat AGPR round-trips
        XELOAD(1);
        { int pn = p + 2 > pe ? pe : p + 2; eS[0] = elist2[pn]; }
        COMPUTE(0);
        if (++p >= p1) break;
        XELOAD(0);
        { int pn = p + 2 > pe ? pe : p + 2; eS[1] = elist2[pn]; }
        COMPUTE(1);
        if (++p >= p1) break;
    }

    float inv = 1.0f / (z + 1e-16f);
    #pragma unroll
    for (int j = 0; j < 4; ++j) {
        float o = fmaf(acc[j], inv, bias[base + 16 * j]);
        if (RELU) o = fmaxf(o, 0.f);
        out[(size_t)n * FEAT + base + 16 * j] = o;
    }
}

// ---------------- gate score: gate[n] = ghid[n,:] @ W2 + b2 ----------------
__global__ __launch_bounds__(256) void k_gate_score(const float* __restrict__ ghid,
    const float* __restrict__ W2, const float* __restrict__ b2, float* __restrict__ gate)
{
    int lane = threadIdx.x & 63;
    int n = blockIdx.x * 4 + (threadIdx.x >> 6);
    float v = ghid[(size_t)n * 128 + lane] * W2[lane] + ghid[(size_t)n * 128 + lane + 64] * W2[lane + 64];
    #pragma unroll
    for (int off = 32; off > 0; off >>= 1) v += __shfl_xor(v, off, 64);
    if (lane == 0) gate[n] = v + b2[0];
}

// ---------------- attentional pooling: one block per batch segment ----------------
__device__ __forceinline__ int lbound(const int* a, int n, int v)
{
    int lo = 0, hi = n;
    while (lo < hi) { int mid = (lo + hi) >> 1; if (a[mid] < v) lo = mid + 1; else hi = mid; }
    return lo;
}

__global__ __launch_bounds__(256) void k_pool(const float* __restrict__ gate,
    const float* __restrict__ h, const int* __restrict__ batch, float* __restrict__ g)
{
    int b = blockIdx.x;
    int t = threadIdx.x;
    __shared__ float red[256];
    int start = lbound(batch, N_NODES, b);
    int end   = lbound(batch, N_NODES, b + 1);

    float mx = -INFINITY;
    for (int n = start + t; n < end; n += 256) mx = fmaxf(mx, gate[n]);
    red[t] = mx; __syncthreads();
    for (int s = 128; s; s >>= 1) { if (t < s) red[t] = fmaxf(red[t], red[t + s]); __syncthreads(); }
    float m = red[0];
    __syncthreads();

    float zs = 0.f;
    for (int n = start + t; n < end; n += 256) zs += __expf(gate[n] - m);
    red[t] = zs; __syncthreads();
    for (int s = 128; s; s >>= 1) { if (t < s) red[t] += red[t + s]; __syncthreads(); }
    float z = red[0];

    float gs = 0.f;
    for (int n = start; n < end; ++n) gs += __expf(gate[n] - m) * h[(size_t)n * FEAT + t];
    g[b * FEAT + t] = gs / (z + 1e-16f);
}

// ---------------- regression head: per-batch tiny MLP ----------------
__global__ __launch_bounds__(128) void k_reg(const float* __restrict__ g,
    const float* __restrict__ W1, const float* __restrict__ b1,
    const float* __restrict__ W2, const float* __restrict__ b2, float* __restrict__ out)
{
    int b = blockIdx.x, t = threadIdx.x;
    __shared__ float sg[FEAT];
    sg[t] = g[b * FEAT + t];
    sg[t + 128] = g[b * FEAT + t + 128];
    __syncthreads();
    float hv = b1[t];
    for (int k = 0; k < FEAT; ++k) hv += sg[k] * W1[k * 128 + t];
    hv = fmaxf(hv, 0.f);
    __shared__ float p0s[128], p1s[128];
    p0s[t] = hv * W2[t * 2 + 0];
    p1s[t] = hv * W2[t * 2 + 1];
    __syncthreads();
    for (int s = 64; s; s >>= 1) {
        if (t < s) { p0s[t] += p0s[t + s]; p1s[t] += p1s[t + s]; }
        __syncthreads();
    }
    if (t == 0) { out[b * 2 + 0] = p0s[0] + b2[0]; out[b * 2 + 1] = p1s[0] + b2[1]; }
}

// ---------------- launch ----------------
extern "C" void kernel_launch(void* const* d_in, const int* in_sizes, int n_in,
                              void* d_out, int out_size, void* d_ws, size_t ws_size,
                              hipStream_t stream)
{
    const float* x       = (const float*)d_in[0];
    const int*   ei      = (const int*)d_in[1];   // [2,E]
    const float* ea      = (const float*)d_in[2];
    const int*   batch   = (const int*)d_in[3];
    const float* c1_Wl   = (const float*)d_in[5];
    const float* c1_bl   = (const float*)d_in[6];
    const float* c1_Wr   = (const float*)d_in[7];
    const float* c1_br   = (const float*)d_in[8];
    const float* c1_We   = (const float*)d_in[9];
    const float* c1_att  = (const float*)d_in[10];
    const float* c1_bias = (const float*)d_in[11];
    const float* c2_Wl   = (const float*)d_in[12];
    const float* c2_bl   = (const float*)d_in[13];
    const float* c2_Wr   = (const float*)d_in[14];
    const float* c2_br   = (const float*)d_in[15];
    const float* c2_We   = (const float*)d_in[16];
    const float* c2_att  = (const float*)d_in[17];
    const float* c2_bias = (const float*)d_in[18];
    const float* c3_Wl   = (const float*)d_in[19];
    const float* c3_bl   = (const float*)d_in[20];
    const float* c3_Wr   = (const float*)d_in[21];
    const float* c3_br   = (const float*)d_in[22];
    const float* c3_We   = (const float*)d_in[23];
    const float* c3_att  = (const float*)d_in[24];
    const float* c3_bias = (const float*)d_in[25];
    const float* gate_W1 = (const float*)d_in[26];
    const float* gate_b1 = (const float*)d_in[27];
    const float* gate_W2 = (const float*)d_in[28];
    const float* gate_b2 = (const float*)d_in[29];
    const float* reg_W1  = (const float*)d_in[30];
    const float* reg_b1  = (const float*)d_in[31];
    const float* reg_W2  = (const float*)d_in[32];
    const float* reg_b2  = (const float*)d_in[33];

    const int* srcArr = ei;            // row 0
    const int* dstArr = ei + N_EDGES;  // row 1

    float* ws = (float*)d_ws;
    size_t off = 0;
    auto alloc = [&](size_t nf) { float* p = ws + off; off += (nf + 63) & ~(size_t)63; return p; };
    float* xl        = alloc((size_t)N_NODES * FEAT);
    float* xr        = alloc((size_t)N_NODES * FEAT);
    float* h         = alloc((size_t)N_NODES * FEAT);
    float* loop_attr = alloc((size_t)N_NODES * ED_DIM);
    float* gpool     = alloc((size_t)BATCH * FEAT);
    int* ibase  = (int*)(ws + off);
    int* deg    = ibase;
    int* fill   = ibase + N_NODES;
    int* rowptr = ibase + 2 * N_NODES;            // N+1 ints
    int* bsum   = ibase + 3 * N_NODES + 64;
    int* boff   = bsum + 256;
    int2* elist2 = (int2*)(boff + 256);           // ETOT int2

    // aliases at disjoint lifetimes
    float* ghid = xl;                       // after L3 gat, xl is dead
    float* gate = xr;

    hipMemsetAsync(deg, 0, (size_t)2 * N_NODES * sizeof(int), stream);

    // CSR build, then self-loop mean attrs from CSR
    k_deg<<<(ETOT + 255) / 256, 256, 0, stream>>>(dstArr, deg);
    k_scan1<<<NCHUNK, 256, 0, stream>>>(deg, bsum);
    k_scan2<<<1, 256, 0, stream>>>(bsum, boff, rowptr);
    k_scan3<<<NCHUNK, 256, 0, stream>>>(deg, boff, rowptr);
    k_fill<<<(ETOT + 255) / 256, 256, 0, stream>>>(srcArr, dstArr, rowptr, fill, elist2);
    k_loop_csr<<<(N_NODES * ED_DIM + 255) / 256, 256, 0, stream>>>(elist2, rowptr, ea, loop_attr);

    // layer 1 (in: x [N,128])
    launch_gemm(x, c1_Wl, c1_bl, xl, N_NODES, FEAT, IN_DIM, 0, stream);
    launch_gemm(x, c1_Wr, c1_br, xr, N_NODES, FEAT, IN_DIM, 0, stream);
    k_gat<4, 1><<<N_NODES / 4, 256, 0, stream>>>(xl, xr, ea, loop_attr, elist2, rowptr,
                                                 c1_We, c1_att, c1_bias, h);
    // layer 2
    launch_gemm(h, c2_Wl, c2_bl, xl, N_NODES, FEAT, FEAT, 0, stream);
    launch_gemm(h, c2_Wr, c2_br, xr, N_NODES, FEAT, FEAT, 0, stream);
    k_gat<4, 1><<<N_NODES / 4, 256, 0, stream>>>(xl, xr, ea, loop_attr, elist2, rowptr,
                                                 c2_We, c2_att, c2_bias, h);
    // layer 3 (heads=1, no relu)
    launch_gemm(h, c3_Wl, c3_bl, xl, N_NODES, FEAT, FEAT, 0, stream);
    launch_gemm(h, c3_Wr, c3_br, xr, N_NODES, FEAT, FEAT, 0, stream);
    k_gat<1, 0><<<N_NODES / 4, 256, 0, stream>>>(xl, xr, ea, loop_attr, elist2, rowptr,
                                                 c3_We, c3_att, c3_bias, h);

    // pooling + head
    launch_gemm(h, gate_W1, gate_b1, ghid, N_NODES, 128, FEAT, 1, stream);
    k_gate_score<<<N_NODES / 4, 256, 0, stream>>>(ghid, gate_W2, gate_b2, gate);
    k_pool<<<BATCH, 256, 0, stream>>>(gate, h, batch, gpool);
    k_reg<<<BATCH, 128, 0, stream>>>(gpool, reg_W1, reg_b1, reg_W2, reg_b2, (float*)d_out);
}